// Round 3
// baseline (1694.594 us; speedup 1.0000x reference)
//
#include <hip/hip_runtime.h>

#define EPS_DENOM 1e-7f
#define EPS_NORM  1e-5f

static constexpr int D  = 32;     // feature dim
static constexpr int H  = 128;    // hidden dim
static constexpr int BK = 128;    // nodes per bucket (bucket = node >> 7)
static constexpr int CHUNK = 3072;    // edges per bin1 block (6144 records, 48 KB LDS)

typedef _Float16 f16x8 __attribute__((ext_vector_type(8)));
typedef float    f32x4 __attribute__((ext_vector_type(4)));

// ---------------------------------------------------------------------------
// FCNN via fp16 MFMA (unchanged — verified). Block = 4 waves = 64 nodes.
// ---------------------------------------------------------------------------
__global__ __launch_bounds__(256) void fcnn_mfma_kernel(
    const float* __restrict__ x,
    const float* __restrict__ W1a, const float* __restrict__ b1a,
    const float* __restrict__ W2a, const float* __restrict__ b2a,
    const float* __restrict__ W1b, const float* __restrict__ b1b,
    const float* __restrict__ W2b, const float* __restrict__ b2b,
    float* __restrict__ h1, _Float16* __restrict__ h2h, int N)
{
    __shared__ _Float16 lds[30208];
    _Float16* xk = lds;

    const int tid = threadIdx.x;
    const int nb0 = blockIdx.x * 64;

    #pragma unroll
    for (int t = 0; t < 8; ++t) {
        int f = t * 256 + tid;
        int node = f >> 5, off = f & 31;
        int gn = nb0 + node;
        float v = (gn < N) ? x[(size_t)gn * 32 + off] : 0.0f;
        xk[node * 40 + off] = (_Float16)v;
    }
    for (int fc = 0; fc < 2; ++fc) {
        const float* W1 = fc ? W1b : W1a;
        const float* W2 = fc ? W2b : W2a;
        _Float16* w1t = lds + 2560 + fc * 5120;    // [h][k], stride 40
        _Float16* w2t = lds + 12800 + fc * 4352;   // [d][k], stride 136
        #pragma unroll
        for (int t = 0; t < 16; ++t) {
            int f = t * 256 + tid;
            w1t[(f & 127) * 40 + (f >> 7)] = (_Float16)W1[f];
        }
        #pragma unroll
        for (int t = 0; t < 16; ++t) {
            int f = t * 256 + tid;
            w2t[(f & 31) * 136 + (f >> 5)] = (_Float16)W2[f];
        }
    }
    __syncthreads();

    const int wid  = tid >> 6;
    const int lane = tid & 63;
    const int m    = lane & 15;
    const int g    = lane >> 4;
    _Float16* t1 = lds + 21504 + wid * 2176;

    f16x8 ax = *(const f16x8*)(xk + (wid * 16 + m) * 40 + g * 8);

    for (int fc = 0; fc < 2; ++fc) {
        const float* b1v = fc ? b1b : b1a;
        const float* b2v = fc ? b2b : b2a;
        const _Float16* w1t = lds + 2560 + fc * 5120;
        const _Float16* w2t = lds + 12800 + fc * 4352;

        for (int hb = 0; hb < 8; ++hb) {
            f16x8 bw = *(const f16x8*)(w1t + (hb * 16 + m) * 40 + g * 8);
            f32x4 c = {0.f, 0.f, 0.f, 0.f};
            c = __builtin_amdgcn_mfma_f32_16x16x32_f16(ax, bw, c, 0, 0, 0);
            float bias = b1v[hb * 16 + m];
            #pragma unroll
            for (int r = 0; r < 4; ++r) {
                float tv = fmaxf(c[r] + bias, 0.0f);
                t1[(g * 4 + r) * 136 + hb * 16 + m] = (_Float16)tv;
            }
        }

        for (int dt = 0; dt < 2; ++dt) {
            f32x4 c2 = {0.f, 0.f, 0.f, 0.f};
            #pragma unroll
            for (int kc = 0; kc < 4; ++kc) {
                f16x8 a2  = *(const f16x8*)(t1 + m * 136 + kc * 32 + g * 8);
                f16x8 b2w = *(const f16x8*)(w2t + (dt * 16 + m) * 136 + kc * 32 + g * 8);
                c2 = __builtin_amdgcn_mfma_f32_16x16x32_f16(a2, b2w, c2, 0, 0, 0);
            }
            float bias = b2v[dt * 16 + m];
            #pragma unroll
            for (int r = 0; r < 4; ++r) {
                int gn = nb0 + wid * 16 + g * 4 + r;
                if (gn < N) {
                    float val = c2[r] + bias;
                    if (fc == 0) h1[(size_t)gn * 32 + dt * 16 + m] = val;
                    else         h2h[(size_t)gn * 32 + dt * 16 + m] = (_Float16)val;
                }
            }
        }
        __syncthreads();
    }
}

// ---------------------------------------------------------------------------
// bin1 (reverted verbatim to the proven R0 form): block-local counting sort
// of 2*CHUNK incidence records by bucket, bucket-grouped coalesced flush to
// per-bucket global segments (runs ~7.9 rec).
// Record: .x = (local7 << 21) | eid21 ; .y = (bucket10 << 17) | nbr17
// ---------------------------------------------------------------------------
__global__ __launch_bounds__(256) void bin1_kernel(
    const int* __restrict__ ei, int* __restrict__ gcursor,
    uint2* __restrict__ gadj, int E, int CAP)
{
    __shared__ uint2 recs[2 * CHUNK];   // 48 KB
    __shared__ int cnt[1024];
    __shared__ int offs[1024];
    __shared__ int gbase[1024];
    __shared__ int partial[256];

    const int tid  = threadIdx.x;
    const int base = blockIdx.x * CHUNK;
    const int ne   = min(CHUNK, E - base);

    #pragma unroll
    for (int i = 0; i < 4; ++i) cnt[tid * 4 + i] = 0;
    __syncthreads();

    int av[CHUNK / 256], bv[CHUNK / 256];
    #pragma unroll
    for (int j = 0; j < CHUNK / 256; ++j) {
        int r = j * 256 + tid;
        if (r < ne) {
            int e = base + r;
            av[j] = ei[e]; bv[j] = ei[E + e];
            atomicAdd(&cnt[av[j] >> 7], 1);
            atomicAdd(&cnt[bv[j] >> 7], 1);
        } else av[j] = -1;
    }
    __syncthreads();

    // exclusive scan of 1024 counters (4 per thread)
    int c0 = cnt[tid*4], c1 = cnt[tid*4+1], c2 = cnt[tid*4+2], c3 = cnt[tid*4+3];
    int psum = c0 + c1 + c2 + c3;
    partial[tid] = psum;
    __syncthreads();
    for (int off = 1; off < 256; off <<= 1) {
        int t = (tid >= off) ? partial[tid - off] : 0;
        __syncthreads();
        partial[tid] += t;
        __syncthreads();
    }
    int ex = partial[tid] - psum;
    offs[tid*4]   = ex;
    offs[tid*4+1] = ex + c0;
    offs[tid*4+2] = ex + c0 + c1;
    offs[tid*4+3] = ex + c0 + c1 + c2;
    cnt[tid*4]    = ex;
    cnt[tid*4+1]  = ex + c0;
    cnt[tid*4+2]  = ex + c0 + c1;
    cnt[tid*4+3]  = ex + c0 + c1 + c2;
    __syncthreads();

    // scatter records into LDS, grouped by bucket
    #pragma unroll
    for (int j = 0; j < CHUNK / 256; ++j) {
        if (av[j] >= 0) {
            int e = base + j * 256 + tid;
            int a = av[j], b = bv[j];
            int pa = atomicAdd(&cnt[a >> 7], 1);
            recs[pa] = make_uint2(((unsigned)(a & 127) << 21) | (unsigned)e,
                                  ((unsigned)(a >> 7) << 17) | (unsigned)b);
            int pb = atomicAdd(&cnt[b >> 7], 1);
            recs[pb] = make_uint2(((unsigned)(b & 127) << 21) | (unsigned)e,
                                  ((unsigned)(b >> 7) << 17) | (unsigned)a);
        }
    }
    __syncthreads();

    // reserve global space per bucket
    #pragma unroll
    for (int i = 0; i < 4; ++i) {
        int bidx = tid * 4 + i;
        int c = cnt[bidx] - offs[bidx];
        if (c > 0) gbase[bidx] = atomicAdd(&gcursor[bidx], c);
    }
    __syncthreads();

    // flush: consecutive records in a bucket -> consecutive global slots
    int total = 2 * ne;
    for (int i = tid; i < total; i += 256) {
        uint2 r = recs[i];
        int bidx = r.y >> 17;
        int dest = gbase[bidx] + (i - offs[bidx]);
        if (dest < CAP)
            gadj[(size_t)bidx * CAP + dest] = r;
    }
}

// ---------------------------------------------------------------------------
// agg: one block per bucket. Streams the bucket's (unsorted) records,
// accumulating s and s*h2 per (local node, dim) into LDS float accumulators
// via ds_add_f32. s = sigmoid(ef[eid]) read directly (random, but full
// 128 B line used). h2h is a 6.4 MB table -> L2-resident. Then finalizes
// h1 + agg, InstanceNorm (32-lane shfl), residual ReLU — all coalesced.
// Replaces bin2 + pay + sprep + gather in one kernel.
// ---------------------------------------------------------------------------
__global__ __launch_bounds__(512) void agg_kernel(
    const int* __restrict__ gcursor, const uint2* __restrict__ gadj,
    const float* __restrict__ ef, const float* __restrict__ x,
    const float* __restrict__ h1, const _Float16* __restrict__ h2h,
    float* __restrict__ out, int N, int CAP)
{
    __shared__ float acc_s [BK * 32];   // 16 KB
    __shared__ float acc_sh[BK * 32];   // 16 KB

    const int tid = threadIdx.x;
    const int bk  = blockIdx.x;
    const int count = min(gcursor[bk], CAP);
    const uint2* seg = gadj + (size_t)bk * CAP;

    for (int i = tid; i < BK * 32; i += 512) {
        acc_s[i]  = 0.0f;
        acc_sh[i] = 0.0f;
    }
    __syncthreads();

    const int g = tid >> 5;    // 16 groups of 32 lanes
    const int d = tid & 31;

    // 2-way unrolled record loop: 2 records in flight per group
    int k = g;
    for (; k + 16 < count; k += 32) {
        uint2 r0 = seg[k];
        uint2 r1 = seg[k + 16];
        int e0 = r0.x & 0x1FFFFF, e1 = r1.x & 0x1FFFFF;
        float v0 = ef[(size_t)e0 * 32 + d];
        float v1 = ef[(size_t)e1 * 32 + d];
        float hv0 = (float)h2h[(size_t)(r0.y & 0x1FFFF) * 32 + d];
        float hv1 = (float)h2h[(size_t)(r1.y & 0x1FFFF) * 32 + d];
        float s0 = 1.0f / (1.0f + __expf(-v0));
        float s1 = 1.0f / (1.0f + __expf(-v1));
        int l0 = (r0.x >> 21) & 127;
        int l1 = (r1.x >> 21) & 127;
        atomicAdd(&acc_s [l0 * 32 + d], s0);
        atomicAdd(&acc_sh[l0 * 32 + d], s0 * hv0);
        atomicAdd(&acc_s [l1 * 32 + d], s1);
        atomicAdd(&acc_sh[l1 * 32 + d], s1 * hv1);
    }
    if (k < count) {
        uint2 r = seg[k];
        int e = r.x & 0x1FFFFF;
        float v = ef[(size_t)e * 32 + d];
        float hv = (float)h2h[(size_t)(r.y & 0x1FFFF) * 32 + d];
        float s = 1.0f / (1.0f + __expf(-v));
        int l = (r.x >> 21) & 127;
        atomicAdd(&acc_s [l * 32 + d], s);
        atomicAdd(&acc_sh[l * 32 + d], s * hv);
    }
    __syncthreads();

    // finalize: 16 groups x 8 nodes each (guards uniform within a group)
    for (int li = g; li < BK; li += 16) {
        int gn = bk * BK + li;
        if (gn >= N) break;
        size_t idx = (size_t)gn * 32 + d;
        float ssum = acc_s [li * 32 + d];
        float shs  = acc_sh[li * 32 + d];
        float h = h1[idx] + shs / (EPS_DENOM + ssum);

        float sum = h, sq = h * h;
        #pragma unroll
        for (int off = 16; off > 0; off >>= 1) {
            sum += __shfl_xor(sum, off, 32);
            sq  += __shfl_xor(sq,  off, 32);
        }
        float mu  = sum * (1.0f / 32.0f);
        float var = fmaxf(sq * (1.0f / 32.0f) - mu * mu, 0.0f);
        float hn  = (h - mu) * rsqrtf(var + EPS_NORM);

        out[idx] = x[idx] + fmaxf(hn, 0.0f);
    }
}

// ---------------------------------------------------------------------------
extern "C" void kernel_launch(void* const* d_in, const int* in_sizes, int n_in,
                              void* d_out, int out_size, void* d_ws, size_t ws_size,
                              hipStream_t stream)
{
    const float* x   = (const float*)d_in[0];
    const float* ef  = (const float*)d_in[1];
    const float* W1a = (const float*)d_in[2];
    const float* b1a = (const float*)d_in[3];
    const float* W2a = (const float*)d_in[4];
    const float* b2a = (const float*)d_in[5];
    const float* W1b = (const float*)d_in[6];
    const float* b1b = (const float*)d_in[7];
    const float* W2b = (const float*)d_in[8];
    const float* b2b = (const float*)d_in[9];
    const int*   ei  = (const int*)d_in[10];
    float* out = (float*)d_out;

    const int N  = in_sizes[0] / D;
    const int E  = in_sizes[1] / D;
    const int NB = (N + BK - 1) / BK;          // buckets (782 for N=100k)
    int CAP = (2 * E) / NB;                    // mean records per bucket
    CAP = CAP + CAP / 2;                       // +50% slack (>>16 sigma)
    CAP = (CAP + 255) & ~255;

    // workspace layout
    char* p = (char*)d_ws;
    float*    h1      = (float*)p;    p += (size_t)N * 32 * 4;
    _Float16* h2h     = (_Float16*)p; p += (size_t)N * 32 * 2;
    int*      gcursor = (int*)p;      p += 1024 * 4;
    p = (char*)(((uintptr_t)p + 31) & ~(uintptr_t)31);
    uint2*    gadj    = (uint2*)p;    p += (size_t)NB * CAP * 8;
    (void)ws_size;

    hipMemsetAsync(gcursor, 0, 1024 * 4, stream);

    fcnn_mfma_kernel<<<(N + 63) / 64, 256, 0, stream>>>(
        x, W1a, b1a, W2a, b2a, W1b, b1b, W2b, b2b, h1, h2h, N);

    bin1_kernel<<<(E + CHUNK - 1) / CHUNK, 256, 0, stream>>>(ei, gcursor, gadj, E, CAP);

    agg_kernel<<<NB, 512, 0, stream>>>(gcursor, gadj, ef, x, h1, h2h, out, N, CAP);
}

// Round 4
// 547.634 us; speedup vs baseline: 3.0944x; 3.0944x over previous
//
#include <hip/hip_runtime.h>

#define EPS_DENOM 1e-7f
#define EPS_NORM  1e-5f

static constexpr int D  = 32;     // feature dim
static constexpr int H  = 128;    // hidden dim
static constexpr int BK = 128;    // nodes per bucket (bucket = node >> 7)
static constexpr int CHUNK = 3072;    // edges per bin1 block (6144 records, 48 KB LDS)
static constexpr int CAPMAX = 6144;   // max records per bucket (bin2 LDS bound)

typedef _Float16 f16x8 __attribute__((ext_vector_type(8)));
typedef float    f32x4 __attribute__((ext_vector_type(4)));

// ---------------------------------------------------------------------------
// FCNN via fp16 MFMA (unchanged — verified). Block = 4 waves = 64 nodes.
// ---------------------------------------------------------------------------
__global__ __launch_bounds__(256) void fcnn_mfma_kernel(
    const float* __restrict__ x,
    const float* __restrict__ W1a, const float* __restrict__ b1a,
    const float* __restrict__ W2a, const float* __restrict__ b2a,
    const float* __restrict__ W1b, const float* __restrict__ b1b,
    const float* __restrict__ W2b, const float* __restrict__ b2b,
    float* __restrict__ h1, _Float16* __restrict__ h2h, int N)
{
    __shared__ _Float16 lds[30208];
    _Float16* xk = lds;

    const int tid = threadIdx.x;
    const int nb0 = blockIdx.x * 64;

    #pragma unroll
    for (int t = 0; t < 8; ++t) {
        int f = t * 256 + tid;
        int node = f >> 5, off = f & 31;
        int gn = nb0 + node;
        float v = (gn < N) ? x[(size_t)gn * 32 + off] : 0.0f;
        xk[node * 40 + off] = (_Float16)v;
    }
    for (int fc = 0; fc < 2; ++fc) {
        const float* W1 = fc ? W1b : W1a;
        const float* W2 = fc ? W2b : W2a;
        _Float16* w1t = lds + 2560 + fc * 5120;    // [h][k], stride 40
        _Float16* w2t = lds + 12800 + fc * 4352;   // [d][k], stride 136
        #pragma unroll
        for (int t = 0; t < 16; ++t) {
            int f = t * 256 + tid;
            w1t[(f & 127) * 40 + (f >> 7)] = (_Float16)W1[f];
        }
        #pragma unroll
        for (int t = 0; t < 16; ++t) {
            int f = t * 256 + tid;
            w2t[(f & 31) * 136 + (f >> 5)] = (_Float16)W2[f];
        }
    }
    __syncthreads();

    const int wid  = tid >> 6;
    const int lane = tid & 63;
    const int m    = lane & 15;
    const int g    = lane >> 4;
    _Float16* t1 = lds + 21504 + wid * 2176;

    f16x8 ax = *(const f16x8*)(xk + (wid * 16 + m) * 40 + g * 8);

    for (int fc = 0; fc < 2; ++fc) {
        const float* b1v = fc ? b1b : b1a;
        const float* b2v = fc ? b2b : b2a;
        const _Float16* w1t = lds + 2560 + fc * 5120;
        const _Float16* w2t = lds + 12800 + fc * 4352;

        for (int hb = 0; hb < 8; ++hb) {
            f16x8 bw = *(const f16x8*)(w1t + (hb * 16 + m) * 40 + g * 8);
            f32x4 c = {0.f, 0.f, 0.f, 0.f};
            c = __builtin_amdgcn_mfma_f32_16x16x32_f16(ax, bw, c, 0, 0, 0);
            float bias = b1v[hb * 16 + m];
            #pragma unroll
            for (int r = 0; r < 4; ++r) {
                float tv = fmaxf(c[r] + bias, 0.0f);
                t1[(g * 4 + r) * 136 + hb * 16 + m] = (_Float16)tv;
            }
        }

        for (int dt = 0; dt < 2; ++dt) {
            f32x4 c2 = {0.f, 0.f, 0.f, 0.f};
            #pragma unroll
            for (int kc = 0; kc < 4; ++kc) {
                f16x8 a2  = *(const f16x8*)(t1 + m * 136 + kc * 32 + g * 8);
                f16x8 b2w = *(const f16x8*)(w2t + (dt * 16 + m) * 136 + kc * 32 + g * 8);
                c2 = __builtin_amdgcn_mfma_f32_16x16x32_f16(a2, b2w, c2, 0, 0, 0);
            }
            float bias = b2v[dt * 16 + m];
            #pragma unroll
            for (int r = 0; r < 4; ++r) {
                int gn = nb0 + wid * 16 + g * 4 + r;
                if (gn < N) {
                    float val = c2[r] + bias;
                    if (fc == 0) h1[(size_t)gn * 32 + dt * 16 + m] = val;
                    else         h2h[(size_t)gn * 32 + dt * 16 + m] = (_Float16)val;
                }
            }
        }
        __syncthreads();
    }
}

// ---------------------------------------------------------------------------
// sigmoid(ef) -> u8 fixed-point (s*255), edge order (coalesced).
// u8 (vs R0's fp16) halves the table to 51 MB -> fully L3-resident, so
// gather's random re-reads hit L3 instead of HBM.
// ---------------------------------------------------------------------------
__global__ __launch_bounds__(256) void sprep_kernel(
    const float* __restrict__ ef, unsigned char* __restrict__ sg8, int n4)
{
    int i = blockIdx.x * blockDim.x + threadIdx.x;
    if (i >= n4) return;
    float4 v = ((const float4*)ef)[i];
    uchar4 q;
    q.x = (unsigned char)(255.0f / (1.0f + __expf(-v.x)) + 0.5f);
    q.y = (unsigned char)(255.0f / (1.0f + __expf(-v.y)) + 0.5f);
    q.z = (unsigned char)(255.0f / (1.0f + __expf(-v.z)) + 0.5f);
    q.w = (unsigned char)(255.0f / (1.0f + __expf(-v.w)) + 0.5f);
    ((uchar4*)sg8)[i] = q;
}

// ---------------------------------------------------------------------------
// bin1 (R0-verbatim): block-local counting sort of 2*CHUNK incidence records
// by bucket, bucket-grouped coalesced flush to per-bucket global segments.
// Record: .x = (local7 << 21) | eid21 ; .y = (bucket10 << 17) | nbr17
// ---------------------------------------------------------------------------
__global__ __launch_bounds__(256) void bin1_kernel(
    const int* __restrict__ ei, int* __restrict__ gcursor,
    uint2* __restrict__ gadj, int E, int CAP)
{
    __shared__ uint2 recs[2 * CHUNK];   // 48 KB
    __shared__ int cnt[1024];
    __shared__ int offs[1024];
    __shared__ int gbase[1024];
    __shared__ int partial[256];

    const int tid  = threadIdx.x;
    const int base = blockIdx.x * CHUNK;
    const int ne   = min(CHUNK, E - base);

    #pragma unroll
    for (int i = 0; i < 4; ++i) cnt[tid * 4 + i] = 0;
    __syncthreads();

    int av[CHUNK / 256], bv[CHUNK / 256];
    #pragma unroll
    for (int j = 0; j < CHUNK / 256; ++j) {
        int r = j * 256 + tid;
        if (r < ne) {
            int e = base + r;
            av[j] = ei[e]; bv[j] = ei[E + e];
            atomicAdd(&cnt[av[j] >> 7], 1);
            atomicAdd(&cnt[bv[j] >> 7], 1);
        } else av[j] = -1;
    }
    __syncthreads();

    // exclusive scan of 1024 counters (4 per thread)
    int c0 = cnt[tid*4], c1 = cnt[tid*4+1], c2 = cnt[tid*4+2], c3 = cnt[tid*4+3];
    int psum = c0 + c1 + c2 + c3;
    partial[tid] = psum;
    __syncthreads();
    for (int off = 1; off < 256; off <<= 1) {
        int t = (tid >= off) ? partial[tid - off] : 0;
        __syncthreads();
        partial[tid] += t;
        __syncthreads();
    }
    int ex = partial[tid] - psum;
    offs[tid*4]   = ex;
    offs[tid*4+1] = ex + c0;
    offs[tid*4+2] = ex + c0 + c1;
    offs[tid*4+3] = ex + c0 + c1 + c2;
    cnt[tid*4]    = ex;
    cnt[tid*4+1]  = ex + c0;
    cnt[tid*4+2]  = ex + c0 + c1;
    cnt[tid*4+3]  = ex + c0 + c1 + c2;
    __syncthreads();

    // scatter records into LDS, grouped by bucket
    #pragma unroll
    for (int j = 0; j < CHUNK / 256; ++j) {
        if (av[j] >= 0) {
            int e = base + j * 256 + tid;
            int a = av[j], b = bv[j];
            int pa = atomicAdd(&cnt[a >> 7], 1);
            recs[pa] = make_uint2(((unsigned)(a & 127) << 21) | (unsigned)e,
                                  ((unsigned)(a >> 7) << 17) | (unsigned)b);
            int pb = atomicAdd(&cnt[b >> 7], 1);
            recs[pb] = make_uint2(((unsigned)(b & 127) << 21) | (unsigned)e,
                                  ((unsigned)(b >> 7) << 17) | (unsigned)a);
        }
    }
    __syncthreads();

    // reserve global space per bucket
    #pragma unroll
    for (int i = 0; i < 4; ++i) {
        int bidx = tid * 4 + i;
        int c = cnt[bidx] - offs[bidx];
        if (c > 0) gbase[bidx] = atomicAdd(&gcursor[bidx], c);
    }
    __syncthreads();

    // flush: consecutive records in a bucket -> consecutive global slots
    int total = 2 * ne;
    for (int i = tid; i < total; i += 256) {
        uint2 r = recs[i];
        int bidx = r.y >> 17;
        int dest = gbase[bidx] + (i - offs[bidx]);
        if (dest < CAP)
            gadj[(size_t)bidx * CAP + dest] = r;
    }
}

// ---------------------------------------------------------------------------
// bin2 (R0-verbatim): per-bucket counting sort -> CSR. One block per bucket.
// ---------------------------------------------------------------------------
__global__ __launch_bounds__(256) void bin2_kernel(
    const int* __restrict__ gcursor, uint2* __restrict__ gadj,
    int* __restrict__ gstart, int* __restrict__ gdeg,
    int N, int CAP)
{
    __shared__ uint2 recs[CAPMAX];   // 48 KB
    __shared__ int cnt[BK];
    __shared__ int sc[BK];
    __shared__ int lcur[BK];

    const int tid = threadIdx.x;
    const int bk  = blockIdx.x;
    const int count = min(gcursor[bk], CAP);
    uint2* seg = gadj + (size_t)bk * CAP;

    if (tid < BK) cnt[tid] = 0;
    for (int i = tid; i < count; i += 256) recs[i] = seg[i];
    __syncthreads();

    for (int i = tid; i < count; i += 256)
        atomicAdd(&cnt[(recs[i].x >> 21) & 127], 1);
    __syncthreads();

    // inclusive scan over 128 counters (Hillis-Steele, barriers uniform)
    int v = (tid < BK) ? cnt[tid] : 0;
    if (tid < BK) sc[tid] = v;
    __syncthreads();
    for (int off = 1; off < BK; off <<= 1) {
        int t = (tid < BK && tid >= off) ? sc[tid - off] : 0;
        __syncthreads();
        if (tid < BK) sc[tid] += t;
        __syncthreads();
    }
    if (tid < BK) {
        int excl = sc[tid] - v;
        lcur[tid] = excl;
        int gn = bk * BK + tid;
        if (gn < N) {
            gstart[gn] = bk * CAP + excl;
            gdeg[gn]   = v;
        }
    }
    __syncthreads();

    for (int i = tid; i < count; i += 256) {
        uint2 r = recs[i];
        int l = (r.x >> 21) & 127;
        int pos = atomicAdd(&lcur[l], 1);
        seg[pos] = make_uint2(r.x & 0x1FFFFFu, r.y & 0x1FFFFu);  // {eid, nbr}
    }
}

// ---------------------------------------------------------------------------
// Gather + finalize (R0 structure). 32 lanes per node (2 nodes/wave).
// USE_SG: s from the u8 table (51 MB, L3-resident).
// ---------------------------------------------------------------------------
template <bool USE_SG>
__global__ __launch_bounds__(256) void gather_kernel(
    const float* __restrict__ x,  const unsigned char* __restrict__ sg8,
    const float* __restrict__ ef, const float* __restrict__ h1,
    const _Float16* __restrict__ h2h,
    const int* __restrict__ gstart, const int* __restrict__ gdeg,
    const uint2* __restrict__ adj2,
    float* __restrict__ out, int N)
{
    int t = blockIdx.x * blockDim.x + threadIdx.x;
    int n = t >> 5;
    int d = t & 31;
    if (n >= N) return;

    int start = gstart[n];
    int end   = start + gdeg[n];

    float s_sum = 0.0f, sh_sum = 0.0f;
    int k = start;
    for (; k + 4 <= end; k += 4) {
        uint2 r0 = adj2[k+0], r1 = adj2[k+1], r2 = adj2[k+2], r3 = adj2[k+3];
        float s0, s1, s2, s3;
        if (USE_SG) {
            s0 = (float)sg8[(size_t)r0.x * 32 + d] * (1.0f / 255.0f);
            s1 = (float)sg8[(size_t)r1.x * 32 + d] * (1.0f / 255.0f);
            s2 = (float)sg8[(size_t)r2.x * 32 + d] * (1.0f / 255.0f);
            s3 = (float)sg8[(size_t)r3.x * 32 + d] * (1.0f / 255.0f);
        } else {
            s0 = 1.0f / (1.0f + __expf(-ef[(size_t)r0.x * 32 + d]));
            s1 = 1.0f / (1.0f + __expf(-ef[(size_t)r1.x * 32 + d]));
            s2 = 1.0f / (1.0f + __expf(-ef[(size_t)r2.x * 32 + d]));
            s3 = 1.0f / (1.0f + __expf(-ef[(size_t)r3.x * 32 + d]));
        }
        float h0 = (float)h2h[(size_t)r0.y * 32 + d];
        float h1v = (float)h2h[(size_t)r1.y * 32 + d];
        float h2v = (float)h2h[(size_t)r2.y * 32 + d];
        float h3 = (float)h2h[(size_t)r3.y * 32 + d];
        s_sum += (s0 + s1) + (s2 + s3);
        sh_sum = fmaf(s0, h0, sh_sum);
        sh_sum = fmaf(s1, h1v, sh_sum);
        sh_sum = fmaf(s2, h2v, sh_sum);
        sh_sum = fmaf(s3, h3, sh_sum);
    }
    for (; k < end; ++k) {
        uint2 r = adj2[k];
        float s;
        if (USE_SG) s = (float)sg8[(size_t)r.x * 32 + d] * (1.0f / 255.0f);
        else        s = 1.0f / (1.0f + __expf(-ef[(size_t)r.x * 32 + d]));
        float hh = (float)h2h[(size_t)r.y * 32 + d];
        s_sum += s;
        sh_sum = fmaf(s, hh, sh_sum);
    }

    size_t idx = (size_t)n * 32 + d;
    float h = h1[idx] + sh_sum / (EPS_DENOM + s_sum);

    float sum = h, sq = h * h;
    #pragma unroll
    for (int off = 16; off > 0; off >>= 1) {
        sum += __shfl_xor(sum, off, 32);
        sq  += __shfl_xor(sq,  off, 32);
    }
    float mu  = sum * (1.0f / 32.0f);
    float var = fmaxf(sq * (1.0f / 32.0f) - mu * mu, 0.0f);
    float hn  = (h - mu) * rsqrtf(var + EPS_NORM);

    out[idx] = x[idx] + fmaxf(hn, 0.0f);
}

// ---------------------------------------------------------------------------
extern "C" void kernel_launch(void* const* d_in, const int* in_sizes, int n_in,
                              void* d_out, int out_size, void* d_ws, size_t ws_size,
                              hipStream_t stream)
{
    const float* x   = (const float*)d_in[0];
    const float* ef  = (const float*)d_in[1];
    const float* W1a = (const float*)d_in[2];
    const float* b1a = (const float*)d_in[3];
    const float* W2a = (const float*)d_in[4];
    const float* b2a = (const float*)d_in[5];
    const float* W1b = (const float*)d_in[6];
    const float* b1b = (const float*)d_in[7];
    const float* W2b = (const float*)d_in[8];
    const float* b2b = (const float*)d_in[9];
    const int*   ei  = (const int*)d_in[10];
    float* out = (float*)d_out;

    const int N  = in_sizes[0] / D;
    const int E  = in_sizes[1] / D;
    const int NB = (N + BK - 1) / BK;          // buckets (782 for N=100k)
    int CAP = (2 * E) / NB;                    // mean records per bucket
    CAP = CAP + CAP / 2;                       // +50% slack (>>16 sigma)
    CAP = (CAP + 255) & ~255;
    if (CAP > CAPMAX) CAP = CAPMAX;

    // workspace layout
    char* p = (char*)d_ws;
    float*    h1      = (float*)p;    p += (size_t)N * 32 * 4;
    _Float16* h2h     = (_Float16*)p; p += (size_t)N * 32 * 2;
    int*      gcursor = (int*)p;      p += 1024 * 4;
    int*      gstart  = (int*)p;      p += (size_t)N * 4;
    int*      gdeg    = (int*)p;      p += (size_t)N * 4;
    p = (char*)(((uintptr_t)p + 31) & ~(uintptr_t)31);
    uint2*    gadj    = (uint2*)p;    p += (size_t)NB * CAP * 8;
    p = (char*)(((uintptr_t)p + 31) & ~(uintptr_t)31);
    unsigned char* sg8 = (unsigned char*)p;
    const bool use_sg = ((size_t)(p - (char*)d_ws) + (size_t)E * 32) <= ws_size;

    hipMemsetAsync(gcursor, 0, 1024 * 4, stream);

    fcnn_mfma_kernel<<<(N + 63) / 64, 256, 0, stream>>>(
        x, W1a, b1a, W2a, b2a, W1b, b1b, W2b, b2b, h1, h2h, N);

    if (use_sg) {
        int n4 = E * 8;
        sprep_kernel<<<(n4 + 255) / 256, 256, 0, stream>>>(ef, sg8, n4);
    }

    bin1_kernel<<<(E + CHUNK - 1) / CHUNK, 256, 0, stream>>>(ei, gcursor, gadj, E, CAP);
    bin2_kernel<<<NB, 256, 0, stream>>>(gcursor, gadj, gstart, gdeg, N, CAP);

    int gthreads = N * 32;
    if (use_sg)
        gather_kernel<true><<<(gthreads + 255) / 256, 256, 0, stream>>>(
            x, sg8, ef, h1, h2h, gstart, gdeg, gadj, out, N);
    else
        gather_kernel<false><<<(gthreads + 255) / 256, 256, 0, stream>>>(
            x, sg8, ef, h1, h2h, gstart, gdeg, gadj, out, N);
}

// Round 5
// 538.969 us; speedup vs baseline: 3.1441x; 1.0161x over previous
//
#include <hip/hip_runtime.h>

#define EPS_DENOM 1e-7f
#define EPS_NORM  1e-5f

static constexpr int D  = 32;     // feature dim
static constexpr int H  = 128;    // hidden dim
static constexpr int BK = 128;    // nodes per bucket (bucket = node >> 7)
static constexpr int CHUNK = 3072;    // edges per bin1 block (6144 records, 48 KB LDS)
static constexpr int CAPMAX = 6144;   // max records per bucket (bin2 LDS bound)

typedef _Float16 f16x8 __attribute__((ext_vector_type(8)));
typedef float    f32x4 __attribute__((ext_vector_type(4)));

// ---------------------------------------------------------------------------
// prep: fused fcnn + sprep + bin1 via block-role striping. Every stripe of 8
// blocks = 3 fcnn + 4 sprep + 1 bin1, so latency-bound bin1 blocks overlap
// with BW-bound sprep and MFMA-bound fcnn instead of running serially.
// All three role bodies are the verified R0/R4 code, verbatim.
// LDS: 62,464 B union (bin1 footprint; fcnn needs 60,416) -> 2 blocks/CU.
// ---------------------------------------------------------------------------
__global__ __launch_bounds__(256) void prep_kernel(
    const float* __restrict__ x,
    const float* __restrict__ W1a, const float* __restrict__ b1a,
    const float* __restrict__ W2a, const float* __restrict__ b2a,
    const float* __restrict__ W1b, const float* __restrict__ b1b,
    const float* __restrict__ W2b, const float* __restrict__ b2b,
    float* __restrict__ h1, _Float16* __restrict__ h2h,
    const float* __restrict__ ef, unsigned char* __restrict__ sg8,
    const int* __restrict__ ei, int* __restrict__ gcursor,
    uint2* __restrict__ gadj,
    int N, int E, int CAP, int F, int B, int stripes, int n4, int do_sg)
{
    __shared__ unsigned long long smem_u64[7808];   // 62,464 B union

    const int tid    = threadIdx.x;
    const int stripe = blockIdx.x >> 3;
    const int slot   = blockIdx.x & 7;

    if (slot < 3) {
        // ----------------------- FCNN role (R4-verbatim) -------------------
        const int fid = stripe * 3 + slot;
        if (fid >= F) return;
        _Float16* lds = (_Float16*)smem_u64;
        _Float16* xk  = lds;
        const int nb0 = fid * 64;

        #pragma unroll
        for (int t = 0; t < 8; ++t) {
            int f = t * 256 + tid;
            int node = f >> 5, off = f & 31;
            int gn = nb0 + node;
            float v = (gn < N) ? x[(size_t)gn * 32 + off] : 0.0f;
            xk[node * 40 + off] = (_Float16)v;
        }
        for (int fc = 0; fc < 2; ++fc) {
            const float* W1 = fc ? W1b : W1a;
            const float* W2 = fc ? W2b : W2a;
            _Float16* w1t = lds + 2560 + fc * 5120;    // [h][k], stride 40
            _Float16* w2t = lds + 12800 + fc * 4352;   // [d][k], stride 136
            #pragma unroll
            for (int t = 0; t < 16; ++t) {
                int f = t * 256 + tid;
                w1t[(f & 127) * 40 + (f >> 7)] = (_Float16)W1[f];
            }
            #pragma unroll
            for (int t = 0; t < 16; ++t) {
                int f = t * 256 + tid;
                w2t[(f & 31) * 136 + (f >> 5)] = (_Float16)W2[f];
            }
        }
        __syncthreads();

        const int wid  = tid >> 6;
        const int lane = tid & 63;
        const int m    = lane & 15;
        const int g    = lane >> 4;
        _Float16* t1 = lds + 21504 + wid * 2176;

        f16x8 ax = *(const f16x8*)(xk + (wid * 16 + m) * 40 + g * 8);

        for (int fc = 0; fc < 2; ++fc) {
            const float* b1v = fc ? b1b : b1a;
            const float* b2v = fc ? b2b : b2a;
            const _Float16* w1t = lds + 2560 + fc * 5120;
            const _Float16* w2t = lds + 12800 + fc * 4352;

            for (int hb = 0; hb < 8; ++hb) {
                f16x8 bw = *(const f16x8*)(w1t + (hb * 16 + m) * 40 + g * 8);
                f32x4 c = {0.f, 0.f, 0.f, 0.f};
                c = __builtin_amdgcn_mfma_f32_16x16x32_f16(ax, bw, c, 0, 0, 0);
                float bias = b1v[hb * 16 + m];
                #pragma unroll
                for (int r = 0; r < 4; ++r) {
                    float tv = fmaxf(c[r] + bias, 0.0f);
                    t1[(g * 4 + r) * 136 + hb * 16 + m] = (_Float16)tv;
                }
            }

            for (int dt = 0; dt < 2; ++dt) {
                f32x4 c2 = {0.f, 0.f, 0.f, 0.f};
                #pragma unroll
                for (int kc = 0; kc < 4; ++kc) {
                    f16x8 a2  = *(const f16x8*)(t1 + m * 136 + kc * 32 + g * 8);
                    f16x8 b2w = *(const f16x8*)(w2t + (dt * 16 + m) * 136 + kc * 32 + g * 8);
                    c2 = __builtin_amdgcn_mfma_f32_16x16x32_f16(a2, b2w, c2, 0, 0, 0);
                }
                float bias = b2v[dt * 16 + m];
                #pragma unroll
                for (int r = 0; r < 4; ++r) {
                    int gn = nb0 + wid * 16 + g * 4 + r;
                    if (gn < N) {
                        float val = c2[r] + bias;
                        if (fc == 0) h1[(size_t)gn * 32 + dt * 16 + m] = val;
                        else         h2h[(size_t)gn * 32 + dt * 16 + m] = (_Float16)val;
                    }
                }
            }
            __syncthreads();
        }
    } else if (slot < 7) {
        // ----------------------- sprep role (grid-stride) ------------------
        if (!do_sg) return;
        const int sid  = stripe * 4 + (slot - 3);
        const int nthr = stripes * 4 * 256;
        const float4* efc = (const float4*)ef;
        uchar4* sq = (uchar4*)sg8;
        int i = sid * 256 + tid;
        for (; i + 3 * nthr < n4; i += 4 * nthr) {
            float4 v0 = efc[i];
            float4 v1 = efc[i + nthr];
            float4 v2 = efc[i + 2 * nthr];
            float4 v3 = efc[i + 3 * nthr];
            uchar4 q0, q1, q2, q3;
            q0.x = (unsigned char)(255.0f / (1.0f + __expf(-v0.x)) + 0.5f);
            q0.y = (unsigned char)(255.0f / (1.0f + __expf(-v0.y)) + 0.5f);
            q0.z = (unsigned char)(255.0f / (1.0f + __expf(-v0.z)) + 0.5f);
            q0.w = (unsigned char)(255.0f / (1.0f + __expf(-v0.w)) + 0.5f);
            q1.x = (unsigned char)(255.0f / (1.0f + __expf(-v1.x)) + 0.5f);
            q1.y = (unsigned char)(255.0f / (1.0f + __expf(-v1.y)) + 0.5f);
            q1.z = (unsigned char)(255.0f / (1.0f + __expf(-v1.z)) + 0.5f);
            q1.w = (unsigned char)(255.0f / (1.0f + __expf(-v1.w)) + 0.5f);
            q2.x = (unsigned char)(255.0f / (1.0f + __expf(-v2.x)) + 0.5f);
            q2.y = (unsigned char)(255.0f / (1.0f + __expf(-v2.y)) + 0.5f);
            q2.z = (unsigned char)(255.0f / (1.0f + __expf(-v2.z)) + 0.5f);
            q2.w = (unsigned char)(255.0f / (1.0f + __expf(-v2.w)) + 0.5f);
            q3.x = (unsigned char)(255.0f / (1.0f + __expf(-v3.x)) + 0.5f);
            q3.y = (unsigned char)(255.0f / (1.0f + __expf(-v3.y)) + 0.5f);
            q3.z = (unsigned char)(255.0f / (1.0f + __expf(-v3.z)) + 0.5f);
            q3.w = (unsigned char)(255.0f / (1.0f + __expf(-v3.w)) + 0.5f);
            sq[i]            = q0;
            sq[i + nthr]     = q1;
            sq[i + 2 * nthr] = q2;
            sq[i + 3 * nthr] = q3;
        }
        for (; i < n4; i += nthr) {
            float4 v = efc[i];
            uchar4 q;
            q.x = (unsigned char)(255.0f / (1.0f + __expf(-v.x)) + 0.5f);
            q.y = (unsigned char)(255.0f / (1.0f + __expf(-v.y)) + 0.5f);
            q.z = (unsigned char)(255.0f / (1.0f + __expf(-v.z)) + 0.5f);
            q.w = (unsigned char)(255.0f / (1.0f + __expf(-v.w)) + 0.5f);
            sq[i] = q;
        }
    } else {
        // ----------------------- bin1 role (R0-verbatim) -------------------
        const int bid = stripe;
        if (bid >= B) return;
        uint2* recs  = (uint2*)smem_u64;                          // 49,152 B
        int* cnt     = (int*)((char*)smem_u64 + 49152);           //  4,096 B
        int* offs    = (int*)((char*)smem_u64 + 53248);           //  4,096 B
        int* gbase   = (int*)((char*)smem_u64 + 57344);           //  4,096 B
        int* partial = (int*)((char*)smem_u64 + 61440);           //  1,024 B

        const int base = bid * CHUNK;
        const int ne   = min(CHUNK, E - base);

        #pragma unroll
        for (int i = 0; i < 4; ++i) cnt[tid * 4 + i] = 0;
        __syncthreads();

        int av[CHUNK / 256], bv[CHUNK / 256];
        #pragma unroll
        for (int j = 0; j < CHUNK / 256; ++j) {
            int r = j * 256 + tid;
            if (r < ne) {
                int e = base + r;
                av[j] = ei[e]; bv[j] = ei[E + e];
                atomicAdd(&cnt[av[j] >> 7], 1);
                atomicAdd(&cnt[bv[j] >> 7], 1);
            } else av[j] = -1;
        }
        __syncthreads();

        // exclusive scan of 1024 counters (4 per thread)
        int c0 = cnt[tid*4], c1 = cnt[tid*4+1], c2 = cnt[tid*4+2], c3 = cnt[tid*4+3];
        int psum = c0 + c1 + c2 + c3;
        partial[tid] = psum;
        __syncthreads();
        for (int off = 1; off < 256; off <<= 1) {
            int t = (tid >= off) ? partial[tid - off] : 0;
            __syncthreads();
            partial[tid] += t;
            __syncthreads();
        }
        int ex = partial[tid] - psum;
        offs[tid*4]   = ex;
        offs[tid*4+1] = ex + c0;
        offs[tid*4+2] = ex + c0 + c1;
        offs[tid*4+3] = ex + c0 + c1 + c2;
        cnt[tid*4]    = ex;
        cnt[tid*4+1]  = ex + c0;
        cnt[tid*4+2]  = ex + c0 + c1;
        cnt[tid*4+3]  = ex + c0 + c1 + c2;
        __syncthreads();

        // scatter records into LDS, grouped by bucket
        #pragma unroll
        for (int j = 0; j < CHUNK / 256; ++j) {
            if (av[j] >= 0) {
                int e = base + j * 256 + tid;
                int a = av[j], b = bv[j];
                int pa = atomicAdd(&cnt[a >> 7], 1);
                recs[pa] = make_uint2(((unsigned)(a & 127) << 21) | (unsigned)e,
                                      ((unsigned)(a >> 7) << 17) | (unsigned)b);
                int pb = atomicAdd(&cnt[b >> 7], 1);
                recs[pb] = make_uint2(((unsigned)(b & 127) << 21) | (unsigned)e,
                                      ((unsigned)(b >> 7) << 17) | (unsigned)a);
            }
        }
        __syncthreads();

        // reserve global space per bucket
        #pragma unroll
        for (int i = 0; i < 4; ++i) {
            int bidx = tid * 4 + i;
            int c = cnt[bidx] - offs[bidx];
            if (c > 0) gbase[bidx] = atomicAdd(&gcursor[bidx], c);
        }
        __syncthreads();

        // flush: consecutive records in a bucket -> consecutive global slots
        int total = 2 * ne;
        for (int i = tid; i < total; i += 256) {
            uint2 r = recs[i];
            int bidx = r.y >> 17;
            int dest = gbase[bidx] + (i - offs[bidx]);
            if (dest < CAP)
                gadj[(size_t)bidx * CAP + dest] = r;
        }
    }
}

// ---------------------------------------------------------------------------
// bin2: per-bucket counting sort -> CSR. One block per bucket.
// NEW: 512 threads (was 256) — LDS ~51 KB allows 3 blocks/CU -> 24 waves/CU,
// halving the serial depth of the staging/scatter loops.
// ---------------------------------------------------------------------------
__global__ __launch_bounds__(512) void bin2_kernel(
    const int* __restrict__ gcursor, uint2* __restrict__ gadj,
    int* __restrict__ gstart, int* __restrict__ gdeg,
    int N, int CAP)
{
    __shared__ uint2 recs[CAPMAX];   // 48 KB
    __shared__ int cnt[BK];
    __shared__ int sc[BK];
    __shared__ int lcur[BK];

    const int tid = threadIdx.x;
    const int bk  = blockIdx.x;
    const int count = min(gcursor[bk], CAP);
    uint2* seg = gadj + (size_t)bk * CAP;

    if (tid < BK) cnt[tid] = 0;
    for (int i = tid; i < count; i += 512) recs[i] = seg[i];
    __syncthreads();

    for (int i = tid; i < count; i += 512)
        atomicAdd(&cnt[(recs[i].x >> 21) & 127], 1);
    __syncthreads();

    // inclusive scan over 128 counters (Hillis-Steele, barriers uniform)
    int v = (tid < BK) ? cnt[tid] : 0;
    if (tid < BK) sc[tid] = v;
    __syncthreads();
    for (int off = 1; off < BK; off <<= 1) {
        int t = (tid < BK && tid >= off) ? sc[tid - off] : 0;
        __syncthreads();
        if (tid < BK) sc[tid] += t;
        __syncthreads();
    }
    if (tid < BK) {
        int excl = sc[tid] - v;
        lcur[tid] = excl;
        int gn = bk * BK + tid;
        if (gn < N) {
            gstart[gn] = bk * CAP + excl;
            gdeg[gn]   = v;
        }
    }
    __syncthreads();

    for (int i = tid; i < count; i += 512) {
        uint2 r = recs[i];
        int l = (r.x >> 21) & 127;
        int pos = atomicAdd(&lcur[l], 1);
        seg[pos] = make_uint2(r.x & 0x1FFFFFu, r.y & 0x1FFFFu);  // {eid, nbr}
    }
}

// ---------------------------------------------------------------------------
// Gather + finalize (R4-verbatim). 32 lanes per node (2 nodes/wave).
// USE_SG: s from the u8 table (51 MB, L3-resident).
// ---------------------------------------------------------------------------
template <bool USE_SG>
__global__ __launch_bounds__(256) void gather_kernel(
    const float* __restrict__ x,  const unsigned char* __restrict__ sg8,
    const float* __restrict__ ef, const float* __restrict__ h1,
    const _Float16* __restrict__ h2h,
    const int* __restrict__ gstart, const int* __restrict__ gdeg,
    const uint2* __restrict__ adj2,
    float* __restrict__ out, int N)
{
    int t = blockIdx.x * blockDim.x + threadIdx.x;
    int n = t >> 5;
    int d = t & 31;
    if (n >= N) return;

    int start = gstart[n];
    int end   = start + gdeg[n];

    float s_sum = 0.0f, sh_sum = 0.0f;
    int k = start;
    for (; k + 4 <= end; k += 4) {
        uint2 r0 = adj2[k+0], r1 = adj2[k+1], r2 = adj2[k+2], r3 = adj2[k+3];
        float s0, s1, s2, s3;
        if (USE_SG) {
            s0 = (float)sg8[(size_t)r0.x * 32 + d] * (1.0f / 255.0f);
            s1 = (float)sg8[(size_t)r1.x * 32 + d] * (1.0f / 255.0f);
            s2 = (float)sg8[(size_t)r2.x * 32 + d] * (1.0f / 255.0f);
            s3 = (float)sg8[(size_t)r3.x * 32 + d] * (1.0f / 255.0f);
        } else {
            s0 = 1.0f / (1.0f + __expf(-ef[(size_t)r0.x * 32 + d]));
            s1 = 1.0f / (1.0f + __expf(-ef[(size_t)r1.x * 32 + d]));
            s2 = 1.0f / (1.0f + __expf(-ef[(size_t)r2.x * 32 + d]));
            s3 = 1.0f / (1.0f + __expf(-ef[(size_t)r3.x * 32 + d]));
        }
        float h0 = (float)h2h[(size_t)r0.y * 32 + d];
        float h1v = (float)h2h[(size_t)r1.y * 32 + d];
        float h2v = (float)h2h[(size_t)r2.y * 32 + d];
        float h3 = (float)h2h[(size_t)r3.y * 32 + d];
        s_sum += (s0 + s1) + (s2 + s3);
        sh_sum = fmaf(s0, h0, sh_sum);
        sh_sum = fmaf(s1, h1v, sh_sum);
        sh_sum = fmaf(s2, h2v, sh_sum);
        sh_sum = fmaf(s3, h3, sh_sum);
    }
    for (; k < end; ++k) {
        uint2 r = adj2[k];
        float s;
        if (USE_SG) s = (float)sg8[(size_t)r.x * 32 + d] * (1.0f / 255.0f);
        else        s = 1.0f / (1.0f + __expf(-ef[(size_t)r.x * 32 + d]));
        float hh = (float)h2h[(size_t)r.y * 32 + d];
        s_sum += s;
        sh_sum = fmaf(s, hh, sh_sum);
    }

    size_t idx = (size_t)n * 32 + d;
    float h = h1[idx] + sh_sum / (EPS_DENOM + s_sum);

    float sum = h, sq = h * h;
    #pragma unroll
    for (int off = 16; off > 0; off >>= 1) {
        sum += __shfl_xor(sum, off, 32);
        sq  += __shfl_xor(sq,  off, 32);
    }
    float mu  = sum * (1.0f / 32.0f);
    float var = fmaxf(sq * (1.0f / 32.0f) - mu * mu, 0.0f);
    float hn  = (h - mu) * rsqrtf(var + EPS_NORM);

    out[idx] = x[idx] + fmaxf(hn, 0.0f);
}

// ---------------------------------------------------------------------------
extern "C" void kernel_launch(void* const* d_in, const int* in_sizes, int n_in,
                              void* d_out, int out_size, void* d_ws, size_t ws_size,
                              hipStream_t stream)
{
    const float* x   = (const float*)d_in[0];
    const float* ef  = (const float*)d_in[1];
    const float* W1a = (const float*)d_in[2];
    const float* b1a = (const float*)d_in[3];
    const float* W2a = (const float*)d_in[4];
    const float* b2a = (const float*)d_in[5];
    const float* W1b = (const float*)d_in[6];
    const float* b1b = (const float*)d_in[7];
    const float* W2b = (const float*)d_in[8];
    const float* b2b = (const float*)d_in[9];
    const int*   ei  = (const int*)d_in[10];
    float* out = (float*)d_out;

    const int N  = in_sizes[0] / D;
    const int E  = in_sizes[1] / D;
    const int NB = (N + BK - 1) / BK;          // buckets (782 for N=100k)
    int CAP = (2 * E) / NB;                    // mean records per bucket
    CAP = CAP + CAP / 2;                       // +50% slack (>>16 sigma)
    CAP = (CAP + 255) & ~255;
    if (CAP > CAPMAX) CAP = CAPMAX;

    // workspace layout
    char* p = (char*)d_ws;
    float*    h1      = (float*)p;    p += (size_t)N * 32 * 4;
    _Float16* h2h     = (_Float16*)p; p += (size_t)N * 32 * 2;
    int*      gcursor = (int*)p;      p += 1024 * 4;
    int*      gstart  = (int*)p;      p += (size_t)N * 4;
    int*      gdeg    = (int*)p;      p += (size_t)N * 4;
    p = (char*)(((uintptr_t)p + 31) & ~(uintptr_t)31);
    uint2*    gadj    = (uint2*)p;    p += (size_t)NB * CAP * 8;
    p = (char*)(((uintptr_t)p + 31) & ~(uintptr_t)31);
    unsigned char* sg8 = (unsigned char*)p;
    const bool use_sg = ((size_t)(p - (char*)d_ws) + (size_t)E * 32) <= ws_size;

    hipMemsetAsync(gcursor, 0, 1024 * 4, stream);

    const int F = (N + 63) / 64;               // fcnn blocks
    const int B = (E + CHUNK - 1) / CHUNK;     // bin1 blocks
    int stripes = (F + 2) / 3;
    if (B > stripes) stripes = B;
    const int n4 = E * 8;                      // float4 count for sprep

    prep_kernel<<<stripes * 8, 256, 0, stream>>>(
        x, W1a, b1a, W2a, b2a, W1b, b1b, W2b, b2b, h1, h2h,
        ef, sg8, ei, gcursor, gadj,
        N, E, CAP, F, B, stripes, n4, use_sg ? 1 : 0);

    bin2_kernel<<<NB, 512, 0, stream>>>(gcursor, gadj, gstart, gdeg, N, CAP);

    int gthreads = N * 32;
    if (use_sg)
        gather_kernel<true><<<(gthreads + 255) / 256, 256, 0, stream>>>(
            x, sg8, ef, h1, h2h, gstart, gdeg, gadj, out, N);
    else
        gather_kernel<false><<<(gthreads + 255) / 256, 256, 0, stream>>>(
            x, sg8, ef, h1, h2h, gstart, gdeg, gadj, out, N);
}

// Round 6
// 531.627 us; speedup vs baseline: 3.1876x; 1.0138x over previous
//
#include <hip/hip_runtime.h>

#define EPS_DENOM 1e-7f
#define EPS_NORM  1e-5f

static constexpr int D  = 32;     // feature dim
static constexpr int H  = 128;    // hidden dim
static constexpr int BK = 128;    // nodes per bucket (bucket = node >> 7)
static constexpr int CHUNK = 3072;    // edges per bin1 block (6144 records, 48 KB LDS)
static constexpr int CAPMAX = 6144;   // max records per bucket (bin2 LDS bound)

typedef _Float16 f16x8 __attribute__((ext_vector_type(8)));
typedef float    f32x4 __attribute__((ext_vector_type(4)));

// ---------------------------------------------------------------------------
// fb: fused fcnn + bin1 (stripe of 4 blocks = 3 fcnn + 1 bin1). Both roles
// need ~60 KB LDS -> 2 blocks/CU with or without fusion, so co-residency is
// free; fcnn's MFMA/VALU work fills bin1's memory-latency stalls.
// sprep is NOT fused (R5 lesson: streaming role at 2 blocks/CU collapses
// to ~1 TB/s; it needs zero-LDS full occupancy).
// ---------------------------------------------------------------------------
__global__ __launch_bounds__(256) void fb_kernel(
    const float* __restrict__ x,
    const float* __restrict__ W1a, const float* __restrict__ b1a,
    const float* __restrict__ W2a, const float* __restrict__ b2a,
    const float* __restrict__ W1b, const float* __restrict__ b1b,
    const float* __restrict__ W2b, const float* __restrict__ b2b,
    float* __restrict__ h1, _Float16* __restrict__ h2h,
    const int* __restrict__ ei, int* __restrict__ gcursor,
    uint2* __restrict__ gadj,
    int N, int E, int CAP, int F, int B)
{
    __shared__ unsigned long long smem_u64[7808];   // 62,464 B union

    const int tid    = threadIdx.x;
    const int stripe = blockIdx.x >> 2;
    const int slot   = blockIdx.x & 3;

    if (slot < 3) {
        // ----------------------- FCNN role (verified, verbatim) ------------
        const int fid = stripe * 3 + slot;
        if (fid >= F) return;
        _Float16* lds = (_Float16*)smem_u64;
        _Float16* xk  = lds;
        const int nb0 = fid * 64;

        #pragma unroll
        for (int t = 0; t < 8; ++t) {
            int f = t * 256 + tid;
            int node = f >> 5, off = f & 31;
            int gn = nb0 + node;
            float v = (gn < N) ? x[(size_t)gn * 32 + off] : 0.0f;
            xk[node * 40 + off] = (_Float16)v;
        }
        for (int fc = 0; fc < 2; ++fc) {
            const float* W1 = fc ? W1b : W1a;
            const float* W2 = fc ? W2b : W2a;
            _Float16* w1t = lds + 2560 + fc * 5120;    // [h][k], stride 40
            _Float16* w2t = lds + 12800 + fc * 4352;   // [d][k], stride 136
            #pragma unroll
            for (int t = 0; t < 16; ++t) {
                int f = t * 256 + tid;
                w1t[(f & 127) * 40 + (f >> 7)] = (_Float16)W1[f];
            }
            #pragma unroll
            for (int t = 0; t < 16; ++t) {
                int f = t * 256 + tid;
                w2t[(f & 31) * 136 + (f >> 5)] = (_Float16)W2[f];
            }
        }
        __syncthreads();

        const int wid  = tid >> 6;
        const int lane = tid & 63;
        const int m    = lane & 15;
        const int g    = lane >> 4;
        _Float16* t1 = lds + 21504 + wid * 2176;

        f16x8 ax = *(const f16x8*)(xk + (wid * 16 + m) * 40 + g * 8);

        for (int fc = 0; fc < 2; ++fc) {
            const float* b1v = fc ? b1b : b1a;
            const float* b2v = fc ? b2b : b2a;
            const _Float16* w1t = lds + 2560 + fc * 5120;
            const _Float16* w2t = lds + 12800 + fc * 4352;

            for (int hb = 0; hb < 8; ++hb) {
                f16x8 bw = *(const f16x8*)(w1t + (hb * 16 + m) * 40 + g * 8);
                f32x4 c = {0.f, 0.f, 0.f, 0.f};
                c = __builtin_amdgcn_mfma_f32_16x16x32_f16(ax, bw, c, 0, 0, 0);
                float bias = b1v[hb * 16 + m];
                #pragma unroll
                for (int r = 0; r < 4; ++r) {
                    float tv = fmaxf(c[r] + bias, 0.0f);
                    t1[(g * 4 + r) * 136 + hb * 16 + m] = (_Float16)tv;
                }
            }

            for (int dt = 0; dt < 2; ++dt) {
                f32x4 c2 = {0.f, 0.f, 0.f, 0.f};
                #pragma unroll
                for (int kc = 0; kc < 4; ++kc) {
                    f16x8 a2  = *(const f16x8*)(t1 + m * 136 + kc * 32 + g * 8);
                    f16x8 b2w = *(const f16x8*)(w2t + (dt * 16 + m) * 136 + kc * 32 + g * 8);
                    c2 = __builtin_amdgcn_mfma_f32_16x16x32_f16(a2, b2w, c2, 0, 0, 0);
                }
                float bias = b2v[dt * 16 + m];
                #pragma unroll
                for (int r = 0; r < 4; ++r) {
                    int gn = nb0 + wid * 16 + g * 4 + r;
                    if (gn < N) {
                        float val = c2[r] + bias;
                        if (fc == 0) h1[(size_t)gn * 32 + dt * 16 + m] = val;
                        else         h2h[(size_t)gn * 32 + dt * 16 + m] = (_Float16)val;
                    }
                }
            }
            __syncthreads();
        }
    } else {
        // ----------------------- bin1 role (R0-verbatim) -------------------
        const int bid = stripe;
        if (bid >= B) return;
        uint2* recs  = (uint2*)smem_u64;                          // 49,152 B
        int* cnt     = (int*)((char*)smem_u64 + 49152);           //  4,096 B
        int* offs    = (int*)((char*)smem_u64 + 53248);           //  4,096 B
        int* gbase   = (int*)((char*)smem_u64 + 57344);           //  4,096 B
        int* partial = (int*)((char*)smem_u64 + 61440);           //  1,024 B

        const int base = bid * CHUNK;
        const int ne   = min(CHUNK, E - base);

        #pragma unroll
        for (int i = 0; i < 4; ++i) cnt[tid * 4 + i] = 0;
        __syncthreads();

        int av[CHUNK / 256], bv[CHUNK / 256];
        #pragma unroll
        for (int j = 0; j < CHUNK / 256; ++j) {
            int r = j * 256 + tid;
            if (r < ne) {
                int e = base + r;
                av[j] = ei[e]; bv[j] = ei[E + e];
                atomicAdd(&cnt[av[j] >> 7], 1);
                atomicAdd(&cnt[bv[j] >> 7], 1);
            } else av[j] = -1;
        }
        __syncthreads();

        // exclusive scan of 1024 counters (4 per thread)
        int c0 = cnt[tid*4], c1 = cnt[tid*4+1], c2 = cnt[tid*4+2], c3 = cnt[tid*4+3];
        int psum = c0 + c1 + c2 + c3;
        partial[tid] = psum;
        __syncthreads();
        for (int off = 1; off < 256; off <<= 1) {
            int t = (tid >= off) ? partial[tid - off] : 0;
            __syncthreads();
            partial[tid] += t;
            __syncthreads();
        }
        int ex = partial[tid] - psum;
        offs[tid*4]   = ex;
        offs[tid*4+1] = ex + c0;
        offs[tid*4+2] = ex + c0 + c1;
        offs[tid*4+3] = ex + c0 + c1 + c2;
        cnt[tid*4]    = ex;
        cnt[tid*4+1]  = ex + c0;
        cnt[tid*4+2]  = ex + c0 + c1;
        cnt[tid*4+3]  = ex + c0 + c1 + c2;
        __syncthreads();

        // scatter records into LDS, grouped by bucket
        #pragma unroll
        for (int j = 0; j < CHUNK / 256; ++j) {
            if (av[j] >= 0) {
                int e = base + j * 256 + tid;
                int a = av[j], b = bv[j];
                int pa = atomicAdd(&cnt[a >> 7], 1);
                recs[pa] = make_uint2(((unsigned)(a & 127) << 21) | (unsigned)e,
                                      ((unsigned)(a >> 7) << 17) | (unsigned)b);
                int pb = atomicAdd(&cnt[b >> 7], 1);
                recs[pb] = make_uint2(((unsigned)(b & 127) << 21) | (unsigned)e,
                                      ((unsigned)(b >> 7) << 17) | (unsigned)a);
            }
        }
        __syncthreads();

        // reserve global space per bucket
        #pragma unroll
        for (int i = 0; i < 4; ++i) {
            int bidx = tid * 4 + i;
            int c = cnt[bidx] - offs[bidx];
            if (c > 0) gbase[bidx] = atomicAdd(&gcursor[bidx], c);
        }
        __syncthreads();

        // flush: consecutive records in a bucket -> consecutive global slots
        int total = 2 * ne;
        for (int i = tid; i < total; i += 256) {
            uint2 r = recs[i];
            int bidx = r.y >> 17;
            int dest = gbase[bidx] + (i - offs[bidx]);
            if (dest < CAP)
                gadj[(size_t)bidx * CAP + dest] = r;
        }
    }
}

// ---------------------------------------------------------------------------
// sigmoid(ef) -> u8 fixed-point (s*255), edge order (coalesced). Zero LDS,
// 16 VGPR -> full occupancy streaming (R5 lesson: must NOT be fused).
// ---------------------------------------------------------------------------
__global__ __launch_bounds__(256) void sprep_kernel(
    const float* __restrict__ ef, unsigned char* __restrict__ sg8, int n4)
{
    int i = blockIdx.x * blockDim.x + threadIdx.x;
    if (i >= n4) return;
    float4 v = ((const float4*)ef)[i];
    uchar4 q;
    q.x = (unsigned char)(255.0f / (1.0f + __expf(-v.x)) + 0.5f);
    q.y = (unsigned char)(255.0f / (1.0f + __expf(-v.y)) + 0.5f);
    q.z = (unsigned char)(255.0f / (1.0f + __expf(-v.z)) + 0.5f);
    q.w = (unsigned char)(255.0f / (1.0f + __expf(-v.w)) + 0.5f);
    ((uchar4*)sg8)[i] = q;
}

// ---------------------------------------------------------------------------
// bin2: per-bucket counting sort -> CSR. 512 threads (verified R5).
// ---------------------------------------------------------------------------
__global__ __launch_bounds__(512) void bin2_kernel(
    const int* __restrict__ gcursor, uint2* __restrict__ gadj,
    int* __restrict__ gstart, int* __restrict__ gdeg,
    int N, int CAP)
{
    __shared__ uint2 recs[CAPMAX];   // 48 KB
    __shared__ int cnt[BK];
    __shared__ int sc[BK];
    __shared__ int lcur[BK];

    const int tid = threadIdx.x;
    const int bk  = blockIdx.x;
    const int count = min(gcursor[bk], CAP);
    uint2* seg = gadj + (size_t)bk * CAP;

    if (tid < BK) cnt[tid] = 0;
    for (int i = tid; i < count; i += 512) recs[i] = seg[i];
    __syncthreads();

    for (int i = tid; i < count; i += 512)
        atomicAdd(&cnt[(recs[i].x >> 21) & 127], 1);
    __syncthreads();

    // inclusive scan over 128 counters (Hillis-Steele, barriers uniform)
    int v = (tid < BK) ? cnt[tid] : 0;
    if (tid < BK) sc[tid] = v;
    __syncthreads();
    for (int off = 1; off < BK; off <<= 1) {
        int t = (tid < BK && tid >= off) ? sc[tid - off] : 0;
        __syncthreads();
        if (tid < BK) sc[tid] += t;
        __syncthreads();
    }
    if (tid < BK) {
        int excl = sc[tid] - v;
        lcur[tid] = excl;
        int gn = bk * BK + tid;
        if (gn < N) {
            gstart[gn] = bk * CAP + excl;
            gdeg[gn]   = v;
        }
    }
    __syncthreads();

    for (int i = tid; i < count; i += 512) {
        uint2 r = recs[i];
        int l = (r.x >> 21) & 127;
        int pos = atomicAdd(&lcur[l], 1);
        seg[pos] = make_uint2(r.x & 0x1FFFFFu, r.y & 0x1FFFFu);  // {eid, nbr}
    }
}

// ---------------------------------------------------------------------------
// Gather + finalize. 32 lanes per node (2 nodes/wave).
// NEW: 8-deep unroll (16 loads in flight/wave) to halve exposed L2/L3
// latency on the dominant loop (mean degree ~32 records/node).
// ---------------------------------------------------------------------------
template <bool USE_SG>
__global__ __launch_bounds__(256) void gather_kernel(
    const float* __restrict__ x,  const unsigned char* __restrict__ sg8,
    const float* __restrict__ ef, const float* __restrict__ h1,
    const _Float16* __restrict__ h2h,
    const int* __restrict__ gstart, const int* __restrict__ gdeg,
    const uint2* __restrict__ adj2,
    float* __restrict__ out, int N)
{
    int t = blockIdx.x * blockDim.x + threadIdx.x;
    int n = t >> 5;
    int d = t & 31;
    if (n >= N) return;

    int start = gstart[n];
    int end   = start + gdeg[n];

    float s_sum = 0.0f, sh_sum = 0.0f;
    int k = start;
    for (; k + 8 <= end; k += 8) {
        uint2 r0 = adj2[k+0], r1 = adj2[k+1], r2 = adj2[k+2], r3 = adj2[k+3];
        uint2 r4 = adj2[k+4], r5 = adj2[k+5], r6 = adj2[k+6], r7 = adj2[k+7];
        float s0, s1, s2, s3, s4, s5, s6, s7;
        if (USE_SG) {
            s0 = (float)sg8[(size_t)r0.x * 32 + d] * (1.0f / 255.0f);
            s1 = (float)sg8[(size_t)r1.x * 32 + d] * (1.0f / 255.0f);
            s2 = (float)sg8[(size_t)r2.x * 32 + d] * (1.0f / 255.0f);
            s3 = (float)sg8[(size_t)r3.x * 32 + d] * (1.0f / 255.0f);
            s4 = (float)sg8[(size_t)r4.x * 32 + d] * (1.0f / 255.0f);
            s5 = (float)sg8[(size_t)r5.x * 32 + d] * (1.0f / 255.0f);
            s6 = (float)sg8[(size_t)r6.x * 32 + d] * (1.0f / 255.0f);
            s7 = (float)sg8[(size_t)r7.x * 32 + d] * (1.0f / 255.0f);
        } else {
            s0 = 1.0f / (1.0f + __expf(-ef[(size_t)r0.x * 32 + d]));
            s1 = 1.0f / (1.0f + __expf(-ef[(size_t)r1.x * 32 + d]));
            s2 = 1.0f / (1.0f + __expf(-ef[(size_t)r2.x * 32 + d]));
            s3 = 1.0f / (1.0f + __expf(-ef[(size_t)r3.x * 32 + d]));
            s4 = 1.0f / (1.0f + __expf(-ef[(size_t)r4.x * 32 + d]));
            s5 = 1.0f / (1.0f + __expf(-ef[(size_t)r5.x * 32 + d]));
            s6 = 1.0f / (1.0f + __expf(-ef[(size_t)r6.x * 32 + d]));
            s7 = 1.0f / (1.0f + __expf(-ef[(size_t)r7.x * 32 + d]));
        }
        float h0 = (float)h2h[(size_t)r0.y * 32 + d];
        float h1v = (float)h2h[(size_t)r1.y * 32 + d];
        float h2v = (float)h2h[(size_t)r2.y * 32 + d];
        float h3 = (float)h2h[(size_t)r3.y * 32 + d];
        float h4 = (float)h2h[(size_t)r4.y * 32 + d];
        float h5 = (float)h2h[(size_t)r5.y * 32 + d];
        float h6 = (float)h2h[(size_t)r6.y * 32 + d];
        float h7 = (float)h2h[(size_t)r7.y * 32 + d];
        s_sum += ((s0 + s1) + (s2 + s3)) + ((s4 + s5) + (s6 + s7));
        sh_sum = fmaf(s0, h0, sh_sum);
        sh_sum = fmaf(s1, h1v, sh_sum);
        sh_sum = fmaf(s2, h2v, sh_sum);
        sh_sum = fmaf(s3, h3, sh_sum);
        sh_sum = fmaf(s4, h4, sh_sum);
        sh_sum = fmaf(s5, h5, sh_sum);
        sh_sum = fmaf(s6, h6, sh_sum);
        sh_sum = fmaf(s7, h7, sh_sum);
    }
    for (; k + 4 <= end; k += 4) {
        uint2 r0 = adj2[k+0], r1 = adj2[k+1], r2 = adj2[k+2], r3 = adj2[k+3];
        float s0, s1, s2, s3;
        if (USE_SG) {
            s0 = (float)sg8[(size_t)r0.x * 32 + d] * (1.0f / 255.0f);
            s1 = (float)sg8[(size_t)r1.x * 32 + d] * (1.0f / 255.0f);
            s2 = (float)sg8[(size_t)r2.x * 32 + d] * (1.0f / 255.0f);
            s3 = (float)sg8[(size_t)r3.x * 32 + d] * (1.0f / 255.0f);
        } else {
            s0 = 1.0f / (1.0f + __expf(-ef[(size_t)r0.x * 32 + d]));
            s1 = 1.0f / (1.0f + __expf(-ef[(size_t)r1.x * 32 + d]));
            s2 = 1.0f / (1.0f + __expf(-ef[(size_t)r2.x * 32 + d]));
            s3 = 1.0f / (1.0f + __expf(-ef[(size_t)r3.x * 32 + d]));
        }
        float h0 = (float)h2h[(size_t)r0.y * 32 + d];
        float h1v = (float)h2h[(size_t)r1.y * 32 + d];
        float h2v = (float)h2h[(size_t)r2.y * 32 + d];
        float h3 = (float)h2h[(size_t)r3.y * 32 + d];
        s_sum += (s0 + s1) + (s2 + s3);
        sh_sum = fmaf(s0, h0, sh_sum);
        sh_sum = fmaf(s1, h1v, sh_sum);
        sh_sum = fmaf(s2, h2v, sh_sum);
        sh_sum = fmaf(s3, h3, sh_sum);
    }
    for (; k < end; ++k) {
        uint2 r = adj2[k];
        float s;
        if (USE_SG) s = (float)sg8[(size_t)r.x * 32 + d] * (1.0f / 255.0f);
        else        s = 1.0f / (1.0f + __expf(-ef[(size_t)r.x * 32 + d]));
        float hh = (float)h2h[(size_t)r.y * 32 + d];
        s_sum += s;
        sh_sum = fmaf(s, hh, sh_sum);
    }

    size_t idx = (size_t)n * 32 + d;
    float h = h1[idx] + sh_sum / (EPS_DENOM + s_sum);

    float sum = h, sq = h * h;
    #pragma unroll
    for (int off = 16; off > 0; off >>= 1) {
        sum += __shfl_xor(sum, off, 32);
        sq  += __shfl_xor(sq,  off, 32);
    }
    float mu  = sum * (1.0f / 32.0f);
    float var = fmaxf(sq * (1.0f / 32.0f) - mu * mu, 0.0f);
    float hn  = (h - mu) * rsqrtf(var + EPS_NORM);

    out[idx] = x[idx] + fmaxf(hn, 0.0f);
}

// ---------------------------------------------------------------------------
extern "C" void kernel_launch(void* const* d_in, const int* in_sizes, int n_in,
                              void* d_out, int out_size, void* d_ws, size_t ws_size,
                              hipStream_t stream)
{
    const float* x   = (const float*)d_in[0];
    const float* ef  = (const float*)d_in[1];
    const float* W1a = (const float*)d_in[2];
    const float* b1a = (const float*)d_in[3];
    const float* W2a = (const float*)d_in[4];
    const float* b2a = (const float*)d_in[5];
    const float* W1b = (const float*)d_in[6];
    const float* b1b = (const float*)d_in[7];
    const float* W2b = (const float*)d_in[8];
    const float* b2b = (const float*)d_in[9];
    const int*   ei  = (const int*)d_in[10];
    float* out = (float*)d_out;

    const int N  = in_sizes[0] / D;
    const int E  = in_sizes[1] / D;
    const int NB = (N + BK - 1) / BK;          // buckets (782 for N=100k)
    int CAP = (2 * E) / NB;                    // mean records per bucket
    CAP = CAP + CAP / 2;                       // +50% slack (>>16 sigma)
    CAP = (CAP + 255) & ~255;
    if (CAP > CAPMAX) CAP = CAPMAX;

    // workspace layout
    char* p = (char*)d_ws;
    float*    h1      = (float*)p;    p += (size_t)N * 32 * 4;
    _Float16* h2h     = (_Float16*)p; p += (size_t)N * 32 * 2;
    int*      gcursor = (int*)p;      p += 1024 * 4;
    int*      gstart  = (int*)p;      p += (size_t)N * 4;
    int*      gdeg    = (int*)p;      p += (size_t)N * 4;
    p = (char*)(((uintptr_t)p + 31) & ~(uintptr_t)31);
    uint2*    gadj    = (uint2*)p;    p += (size_t)NB * CAP * 8;
    p = (char*)(((uintptr_t)p + 31) & ~(uintptr_t)31);
    unsigned char* sg8 = (unsigned char*)p;
    const bool use_sg = ((size_t)(p - (char*)d_ws) + (size_t)E * 32) <= ws_size;

    hipMemsetAsync(gcursor, 0, 1024 * 4, stream);

    const int F = (N + 63) / 64;               // fcnn blocks (1563)
    const int B = (E + CHUNK - 1) / CHUNK;     // bin1 blocks (521)
    int stripes = (F + 2) / 3;
    if (B > stripes) stripes = B;

    if (use_sg) {
        int n4 = E * 8;
        sprep_kernel<<<(n4 + 255) / 256, 256, 0, stream>>>(ef, sg8, n4);
    }

    fb_kernel<<<stripes * 4, 256, 0, stream>>>(
        x, W1a, b1a, W2a, b2a, W1b, b1b, W2b, b2b, h1, h2h,
        ei, gcursor, gadj, N, E, CAP, F, B);

    bin2_kernel<<<NB, 512, 0, stream>>>(gcursor, gadj, gstart, gdeg, N, CAP);

    int gthreads = N * 32;
    if (use_sg)
        gather_kernel<true><<<(gthreads + 255) / 256, 256, 0, stream>>>(
            x, sg8, ef, h1, h2h, gstart, gdeg, gadj, out, N);
    else
        gather_kernel<false><<<(gthreads + 255) / 256, 256, 0, stream>>>(
            x, sg8, ef, h1, h2h, gstart, gdeg, gadj, out, N);
}

// Round 7
// 527.982 us; speedup vs baseline: 3.2096x; 1.0069x over previous
//
#include <hip/hip_runtime.h>

#define EPS_DENOM 1e-7f
#define EPS_NORM  1e-5f

static constexpr int D  = 32;     // feature dim
static constexpr int H  = 128;    // hidden dim
static constexpr int BK = 128;    // nodes per bucket (bucket = node >> 7)
static constexpr int CHUNKB = 2304;   // edges per bin1 block (4608 records, 36 KB LDS)
static constexpr int CAPMAX = 6144;   // max records per bucket (bin2 LDS bound)

typedef _Float16 f16x8 __attribute__((ext_vector_type(8)));
typedef float    f32x4 __attribute__((ext_vector_type(4)));

// ---------------------------------------------------------------------------
// fb: fused fcnn + bin1. R7 change: LDS union shrunk 62,464 -> 50,176 B so
// the kernel gets 3 blocks/CU (12 waves) instead of 2 (8 waves) — bin1 is
// latency-bound and needs co-resident waves to hide its stalls.
//  - fcnn: weights staged per-fc sequentially (one buffer pair, 41,472 B)
//  - bin1: CHUNK 3072 -> 2304 (50,176 B)
// ---------------------------------------------------------------------------
__global__ __launch_bounds__(256) void fb_kernel(
    const float* __restrict__ x,
    const float* __restrict__ W1a, const float* __restrict__ b1a,
    const float* __restrict__ W2a, const float* __restrict__ b2a,
    const float* __restrict__ W1b, const float* __restrict__ b1b,
    const float* __restrict__ W2b, const float* __restrict__ b2b,
    float* __restrict__ h1, _Float16* __restrict__ h2h,
    const int* __restrict__ ei, int* __restrict__ gcursor,
    uint2* __restrict__ gadj,
    int N, int E, int CAP, int F, int B)
{
    __shared__ unsigned long long smem_u64[6272];   // 50,176 B union

    const int tid    = threadIdx.x;
    const int stripe = blockIdx.x >> 2;
    const int slot   = blockIdx.x & 3;

    if (slot < 3) {
        // ----------------------- FCNN role (sequential-fc weights) ---------
        const int fid = stripe * 3 + slot;
        if (fid >= F) return;
        _Float16* lds = (_Float16*)smem_u64;
        _Float16* xk  = lds;                    // [64][40]   5,120 B
        _Float16* w1t = lds + 2560;             // [128][40] 10,240 B
        _Float16* w2t = lds + 7680;             // [32][136]  8,704 B
        const int nb0 = fid * 64;

        #pragma unroll
        for (int t = 0; t < 8; ++t) {
            int f = t * 256 + tid;
            int node = f >> 5, off = f & 31;
            int gn = nb0 + node;
            float v = (gn < N) ? x[(size_t)gn * 32 + off] : 0.0f;
            xk[node * 40 + off] = (_Float16)v;
        }
        __syncthreads();

        const int wid  = tid >> 6;
        const int lane = tid & 63;
        const int m    = lane & 15;
        const int g    = lane >> 4;
        _Float16* t1 = lds + 12032 + wid * 2176;   // 4 x 4,352 B = 17,408 B

        f16x8 ax = *(const f16x8*)(xk + (wid * 16 + m) * 40 + g * 8);

        for (int fc = 0; fc < 2; ++fc) {
            const float* W1  = fc ? W1b : W1a;
            const float* W2  = fc ? W2b : W2a;
            const float* b1v = fc ? b1b : b1a;
            const float* b2v = fc ? b2b : b2a;

            if (fc) __syncthreads();   // all waves done reading prev weights
            #pragma unroll
            for (int t = 0; t < 16; ++t) {
                int f = t * 256 + tid;
                w1t[(f & 127) * 40 + (f >> 7)] = (_Float16)W1[f];
            }
            #pragma unroll
            for (int t = 0; t < 16; ++t) {
                int f = t * 256 + tid;
                w2t[(f & 31) * 136 + (f >> 5)] = (_Float16)W2[f];
            }
            __syncthreads();           // weights staged

            for (int hb = 0; hb < 8; ++hb) {
                f16x8 bw = *(const f16x8*)(w1t + (hb * 16 + m) * 40 + g * 8);
                f32x4 c = {0.f, 0.f, 0.f, 0.f};
                c = __builtin_amdgcn_mfma_f32_16x16x32_f16(ax, bw, c, 0, 0, 0);
                float bias = b1v[hb * 16 + m];
                #pragma unroll
                for (int r = 0; r < 4; ++r) {
                    float tv = fmaxf(c[r] + bias, 0.0f);
                    t1[(g * 4 + r) * 136 + hb * 16 + m] = (_Float16)tv;
                }
            }

            for (int dt = 0; dt < 2; ++dt) {
                f32x4 c2 = {0.f, 0.f, 0.f, 0.f};
                #pragma unroll
                for (int kc = 0; kc < 4; ++kc) {
                    f16x8 a2  = *(const f16x8*)(t1 + m * 136 + kc * 32 + g * 8);
                    f16x8 b2w = *(const f16x8*)(w2t + (dt * 16 + m) * 136 + kc * 32 + g * 8);
                    c2 = __builtin_amdgcn_mfma_f32_16x16x32_f16(a2, b2w, c2, 0, 0, 0);
                }
                float bias = b2v[dt * 16 + m];
                #pragma unroll
                for (int r = 0; r < 4; ++r) {
                    int gn = nb0 + wid * 16 + g * 4 + r;
                    if (gn < N) {
                        float val = c2[r] + bias;
                        if (fc == 0) h1[(size_t)gn * 32 + dt * 16 + m] = val;
                        else         h2h[(size_t)gn * 32 + dt * 16 + m] = (_Float16)val;
                    }
                }
            }
        }
    } else {
        // ----------------------- bin1 role (R0 logic, CHUNKB=2304) ---------
        const int bid = stripe;
        if (bid >= B) return;
        uint2* recs  = (uint2*)smem_u64;                          // 36,864 B
        int* cnt     = (int*)((char*)smem_u64 + 36864);           //  4,096 B
        int* offs    = (int*)((char*)smem_u64 + 40960);           //  4,096 B
        int* gbase   = (int*)((char*)smem_u64 + 45056);           //  4,096 B
        int* partial = (int*)((char*)smem_u64 + 49152);           //  1,024 B

        const int base = bid * CHUNKB;
        const int ne   = min(CHUNKB, E - base);

        #pragma unroll
        for (int i = 0; i < 4; ++i) cnt[tid * 4 + i] = 0;
        __syncthreads();

        int av[CHUNKB / 256], bv[CHUNKB / 256];
        #pragma unroll
        for (int j = 0; j < CHUNKB / 256; ++j) {
            int r = j * 256 + tid;
            if (r < ne) {
                int e = base + r;
                av[j] = ei[e]; bv[j] = ei[E + e];
                atomicAdd(&cnt[av[j] >> 7], 1);
                atomicAdd(&cnt[bv[j] >> 7], 1);
            } else av[j] = -1;
        }
        __syncthreads();

        // exclusive scan of 1024 counters (4 per thread)
        int c0 = cnt[tid*4], c1 = cnt[tid*4+1], c2 = cnt[tid*4+2], c3 = cnt[tid*4+3];
        int psum = c0 + c1 + c2 + c3;
        partial[tid] = psum;
        __syncthreads();
        for (int off = 1; off < 256; off <<= 1) {
            int t = (tid >= off) ? partial[tid - off] : 0;
            __syncthreads();
            partial[tid] += t;
            __syncthreads();
        }
        int ex = partial[tid] - psum;
        offs[tid*4]   = ex;
        offs[tid*4+1] = ex + c0;
        offs[tid*4+2] = ex + c0 + c1;
        offs[tid*4+3] = ex + c0 + c1 + c2;
        cnt[tid*4]    = ex;
        cnt[tid*4+1]  = ex + c0;
        cnt[tid*4+2]  = ex + c0 + c1;
        cnt[tid*4+3]  = ex + c0 + c1 + c2;
        __syncthreads();

        // scatter records into LDS, grouped by bucket
        #pragma unroll
        for (int j = 0; j < CHUNKB / 256; ++j) {
            if (av[j] >= 0) {
                int e = base + j * 256 + tid;
                int a = av[j], b = bv[j];
                int pa = atomicAdd(&cnt[a >> 7], 1);
                recs[pa] = make_uint2(((unsigned)(a & 127) << 21) | (unsigned)e,
                                      ((unsigned)(a >> 7) << 17) | (unsigned)b);
                int pb = atomicAdd(&cnt[b >> 7], 1);
                recs[pb] = make_uint2(((unsigned)(b & 127) << 21) | (unsigned)e,
                                      ((unsigned)(b >> 7) << 17) | (unsigned)a);
            }
        }
        __syncthreads();

        // reserve global space per bucket
        #pragma unroll
        for (int i = 0; i < 4; ++i) {
            int bidx = tid * 4 + i;
            int c = cnt[bidx] - offs[bidx];
            if (c > 0) gbase[bidx] = atomicAdd(&gcursor[bidx], c);
        }
        __syncthreads();

        // flush: consecutive records in a bucket -> consecutive global slots
        int total = 2 * ne;
        for (int i = tid; i < total; i += 256) {
            uint2 r = recs[i];
            int bidx = r.y >> 17;
            int dest = gbase[bidx] + (i - offs[bidx]);
            if (dest < CAP)
                gadj[(size_t)bidx * CAP + dest] = r;
        }
    }
}

// ---------------------------------------------------------------------------
// sigmoid(ef) -> u8 fixed-point (s*255), edge order (coalesced). Zero LDS,
// full occupancy streaming (R5 lesson: must NOT be fused under fat LDS).
// ---------------------------------------------------------------------------
__global__ __launch_bounds__(256) void sprep_kernel(
    const float* __restrict__ ef, unsigned char* __restrict__ sg8, int n4)
{
    int i = blockIdx.x * blockDim.x + threadIdx.x;
    if (i >= n4) return;
    float4 v = ((const float4*)ef)[i];
    uchar4 q;
    q.x = (unsigned char)(255.0f / (1.0f + __expf(-v.x)) + 0.5f);
    q.y = (unsigned char)(255.0f / (1.0f + __expf(-v.y)) + 0.5f);
    q.z = (unsigned char)(255.0f / (1.0f + __expf(-v.z)) + 0.5f);
    q.w = (unsigned char)(255.0f / (1.0f + __expf(-v.w)) + 0.5f);
    ((uchar4*)sg8)[i] = q;
}

// ---------------------------------------------------------------------------
// bin2: per-bucket counting sort -> CSR. 512 threads (verified R5).
// ---------------------------------------------------------------------------
__global__ __launch_bounds__(512) void bin2_kernel(
    const int* __restrict__ gcursor, uint2* __restrict__ gadj,
    int* __restrict__ gstart, int* __restrict__ gdeg,
    int N, int CAP)
{
    __shared__ uint2 recs[CAPMAX];   // 48 KB
    __shared__ int cnt[BK];
    __shared__ int sc[BK];
    __shared__ int lcur[BK];

    const int tid = threadIdx.x;
    const int bk  = blockIdx.x;
    const int count = min(gcursor[bk], CAP);
    uint2* seg = gadj + (size_t)bk * CAP;

    if (tid < BK) cnt[tid] = 0;
    for (int i = tid; i < count; i += 512) recs[i] = seg[i];
    __syncthreads();

    for (int i = tid; i < count; i += 512)
        atomicAdd(&cnt[(recs[i].x >> 21) & 127], 1);
    __syncthreads();

    // inclusive scan over 128 counters (Hillis-Steele, barriers uniform)
    int v = (tid < BK) ? cnt[tid] : 0;
    if (tid < BK) sc[tid] = v;
    __syncthreads();
    for (int off = 1; off < BK; off <<= 1) {
        int t = (tid < BK && tid >= off) ? sc[tid - off] : 0;
        __syncthreads();
        if (tid < BK) sc[tid] += t;
        __syncthreads();
    }
    if (tid < BK) {
        int excl = sc[tid] - v;
        lcur[tid] = excl;
        int gn = bk * BK + tid;
        if (gn < N) {
            gstart[gn] = bk * CAP + excl;
            gdeg[gn]   = v;
        }
    }
    __syncthreads();

    for (int i = tid; i < count; i += 512) {
        uint2 r = recs[i];
        int l = (r.x >> 21) & 127;
        int pos = atomicAdd(&lcur[l], 1);
        seg[pos] = make_uint2(r.x & 0x1FFFFFu, r.y & 0x1FFFFu);  // {eid, nbr}
    }
}

// ---------------------------------------------------------------------------
// Gather + finalize (R6-verbatim). 32 lanes per node, 8-deep unroll.
// ---------------------------------------------------------------------------
template <bool USE_SG>
__global__ __launch_bounds__(256) void gather_kernel(
    const float* __restrict__ x,  const unsigned char* __restrict__ sg8,
    const float* __restrict__ ef, const float* __restrict__ h1,
    const _Float16* __restrict__ h2h,
    const int* __restrict__ gstart, const int* __restrict__ gdeg,
    const uint2* __restrict__ adj2,
    float* __restrict__ out, int N)
{
    int t = blockIdx.x * blockDim.x + threadIdx.x;
    int n = t >> 5;
    int d = t & 31;
    if (n >= N) return;

    int start = gstart[n];
    int end   = start + gdeg[n];

    float s_sum = 0.0f, sh_sum = 0.0f;
    int k = start;
    for (; k + 8 <= end; k += 8) {
        uint2 r0 = adj2[k+0], r1 = adj2[k+1], r2 = adj2[k+2], r3 = adj2[k+3];
        uint2 r4 = adj2[k+4], r5 = adj2[k+5], r6 = adj2[k+6], r7 = adj2[k+7];
        float s0, s1, s2, s3, s4, s5, s6, s7;
        if (USE_SG) {
            s0 = (float)sg8[(size_t)r0.x * 32 + d] * (1.0f / 255.0f);
            s1 = (float)sg8[(size_t)r1.x * 32 + d] * (1.0f / 255.0f);
            s2 = (float)sg8[(size_t)r2.x * 32 + d] * (1.0f / 255.0f);
            s3 = (float)sg8[(size_t)r3.x * 32 + d] * (1.0f / 255.0f);
            s4 = (float)sg8[(size_t)r4.x * 32 + d] * (1.0f / 255.0f);
            s5 = (float)sg8[(size_t)r5.x * 32 + d] * (1.0f / 255.0f);
            s6 = (float)sg8[(size_t)r6.x * 32 + d] * (1.0f / 255.0f);
            s7 = (float)sg8[(size_t)r7.x * 32 + d] * (1.0f / 255.0f);
        } else {
            s0 = 1.0f / (1.0f + __expf(-ef[(size_t)r0.x * 32 + d]));
            s1 = 1.0f / (1.0f + __expf(-ef[(size_t)r1.x * 32 + d]));
            s2 = 1.0f / (1.0f + __expf(-ef[(size_t)r2.x * 32 + d]));
            s3 = 1.0f / (1.0f + __expf(-ef[(size_t)r3.x * 32 + d]));
            s4 = 1.0f / (1.0f + __expf(-ef[(size_t)r4.x * 32 + d]));
            s5 = 1.0f / (1.0f + __expf(-ef[(size_t)r5.x * 32 + d]));
            s6 = 1.0f / (1.0f + __expf(-ef[(size_t)r6.x * 32 + d]));
            s7 = 1.0f / (1.0f + __expf(-ef[(size_t)r7.x * 32 + d]));
        }
        float h0 = (float)h2h[(size_t)r0.y * 32 + d];
        float h1v = (float)h2h[(size_t)r1.y * 32 + d];
        float h2v = (float)h2h[(size_t)r2.y * 32 + d];
        float h3 = (float)h2h[(size_t)r3.y * 32 + d];
        float h4 = (float)h2h[(size_t)r4.y * 32 + d];
        float h5 = (float)h2h[(size_t)r5.y * 32 + d];
        float h6 = (float)h2h[(size_t)r6.y * 32 + d];
        float h7 = (float)h2h[(size_t)r7.y * 32 + d];
        s_sum += ((s0 + s1) + (s2 + s3)) + ((s4 + s5) + (s6 + s7));
        sh_sum = fmaf(s0, h0, sh_sum);
        sh_sum = fmaf(s1, h1v, sh_sum);
        sh_sum = fmaf(s2, h2v, sh_sum);
        sh_sum = fmaf(s3, h3, sh_sum);
        sh_sum = fmaf(s4, h4, sh_sum);
        sh_sum = fmaf(s5, h5, sh_sum);
        sh_sum = fmaf(s6, h6, sh_sum);
        sh_sum = fmaf(s7, h7, sh_sum);
    }
    for (; k + 4 <= end; k += 4) {
        uint2 r0 = adj2[k+0], r1 = adj2[k+1], r2 = adj2[k+2], r3 = adj2[k+3];
        float s0, s1, s2, s3;
        if (USE_SG) {
            s0 = (float)sg8[(size_t)r0.x * 32 + d] * (1.0f / 255.0f);
            s1 = (float)sg8[(size_t)r1.x * 32 + d] * (1.0f / 255.0f);
            s2 = (float)sg8[(size_t)r2.x * 32 + d] * (1.0f / 255.0f);
            s3 = (float)sg8[(size_t)r3.x * 32 + d] * (1.0f / 255.0f);
        } else {
            s0 = 1.0f / (1.0f + __expf(-ef[(size_t)r0.x * 32 + d]));
            s1 = 1.0f / (1.0f + __expf(-ef[(size_t)r1.x * 32 + d]));
            s2 = 1.0f / (1.0f + __expf(-ef[(size_t)r2.x * 32 + d]));
            s3 = 1.0f / (1.0f + __expf(-ef[(size_t)r3.x * 32 + d]));
        }
        float h0 = (float)h2h[(size_t)r0.y * 32 + d];
        float h1v = (float)h2h[(size_t)r1.y * 32 + d];
        float h2v = (float)h2h[(size_t)r2.y * 32 + d];
        float h3 = (float)h2h[(size_t)r3.y * 32 + d];
        s_sum += (s0 + s1) + (s2 + s3);
        sh_sum = fmaf(s0, h0, sh_sum);
        sh_sum = fmaf(s1, h1v, sh_sum);
        sh_sum = fmaf(s2, h2v, sh_sum);
        sh_sum = fmaf(s3, h3, sh_sum);
    }
    for (; k < end; ++k) {
        uint2 r = adj2[k];
        float s;
        if (USE_SG) s = (float)sg8[(size_t)r.x * 32 + d] * (1.0f / 255.0f);
        else        s = 1.0f / (1.0f + __expf(-ef[(size_t)r.x * 32 + d]));
        float hh = (float)h2h[(size_t)r.y * 32 + d];
        s_sum += s;
        sh_sum = fmaf(s, hh, sh_sum);
    }

    size_t idx = (size_t)n * 32 + d;
    float h = h1[idx] + sh_sum / (EPS_DENOM + s_sum);

    float sum = h, sq = h * h;
    #pragma unroll
    for (int off = 16; off > 0; off >>= 1) {
        sum += __shfl_xor(sum, off, 32);
        sq  += __shfl_xor(sq,  off, 32);
    }
    float mu  = sum * (1.0f / 32.0f);
    float var = fmaxf(sq * (1.0f / 32.0f) - mu * mu, 0.0f);
    float hn  = (h - mu) * rsqrtf(var + EPS_NORM);

    out[idx] = x[idx] + fmaxf(hn, 0.0f);
}

// ---------------------------------------------------------------------------
extern "C" void kernel_launch(void* const* d_in, const int* in_sizes, int n_in,
                              void* d_out, int out_size, void* d_ws, size_t ws_size,
                              hipStream_t stream)
{
    const float* x   = (const float*)d_in[0];
    const float* ef  = (const float*)d_in[1];
    const float* W1a = (const float*)d_in[2];
    const float* b1a = (const float*)d_in[3];
    const float* W2a = (const float*)d_in[4];
    const float* b2a = (const float*)d_in[5];
    const float* W1b = (const float*)d_in[6];
    const float* b1b = (const float*)d_in[7];
    const float* W2b = (const float*)d_in[8];
    const float* b2b = (const float*)d_in[9];
    const int*   ei  = (const int*)d_in[10];
    float* out = (float*)d_out;

    const int N  = in_sizes[0] / D;
    const int E  = in_sizes[1] / D;
    const int NB = (N + BK - 1) / BK;          // buckets (782 for N=100k)
    int CAP = (2 * E) / NB;                    // mean records per bucket
    CAP = CAP + CAP / 2;                       // +50% slack (>>16 sigma)
    CAP = (CAP + 255) & ~255;
    if (CAP > CAPMAX) CAP = CAPMAX;

    // workspace layout
    char* p = (char*)d_ws;
    float*    h1      = (float*)p;    p += (size_t)N * 32 * 4;
    _Float16* h2h     = (_Float16*)p; p += (size_t)N * 32 * 2;
    int*      gcursor = (int*)p;      p += 1024 * 4;
    int*      gstart  = (int*)p;      p += (size_t)N * 4;
    int*      gdeg    = (int*)p;      p += (size_t)N * 4;
    p = (char*)(((uintptr_t)p + 31) & ~(uintptr_t)31);
    uint2*    gadj    = (uint2*)p;    p += (size_t)NB * CAP * 8;
    p = (char*)(((uintptr_t)p + 31) & ~(uintptr_t)31);
    unsigned char* sg8 = (unsigned char*)p;
    const bool use_sg = ((size_t)(p - (char*)d_ws) + (size_t)E * 32) <= ws_size;

    hipMemsetAsync(gcursor, 0, 1024 * 4, stream);

    const int F = (N + 63) / 64;               // fcnn blocks (1563)
    const int B = (E + CHUNKB - 1) / CHUNKB;   // bin1 blocks (695)
    int stripes = (F + 2) / 3;
    if (B > stripes) stripes = B;

    if (use_sg) {
        int n4 = E * 8;
        sprep_kernel<<<(n4 + 255) / 256, 256, 0, stream>>>(ef, sg8, n4);
    }

    fb_kernel<<<stripes * 4, 256, 0, stream>>>(
        x, W1a, b1a, W2a, b2a, W1b, b1b, W2b, b2b, h1, h2h,
        ei, gcursor, gadj, N, E, CAP, F, B);

    bin2_kernel<<<NB, 512, 0, stream>>>(gcursor, gadj, gstart, gdeg, N, CAP);

    int gthreads = N * 32;
    if (use_sg)
        gather_kernel<true><<<(gthreads + 255) / 256, 256, 0, stream>>>(
            x, sg8, ef, h1, h2h, gstart, gdeg, gadj, out, N);
    else
        gather_kernel<false><<<(gthreads + 255) / 256, 256, 0, stream>>>(
            x, sg8, ef, h1, h2h, gstart, gdeg, gadj, out, N);
}